// Round 2
// baseline (154.419 us; speedup 1.0000x reference)
//
#include <hip/hip_runtime.h>
#include <math.h>

// CRF loss: B=256, L=256, T=50.
// R12: fwd+bwd chains INTERLEAVED in one wave + full fusion (1 kernel).
//   R10/R11 were latency-bound: 1 serial chain per wave, ~1000 cy/step,
//   per-active-SIMD VALU issue ~38%, MfmaUtil 5.5%. R12 runs the two
//   independent chains (fwd: u = v0.M1..M127, bwd: w = M128..M255.1) in
//   the SAME wave so each chain's MFMA/VALU latency hides under the other
//   chain's issue. Block b handles batch b entirely: scan both halves,
//   then dot(u,w), gold score, and out[b] in-kernel (no ws, no 2nd launch).
//   MFMA pair is independent + VALU add (R10 style, not R11's chained acc).
// Recurrence is R11's verified lane-local form: A = E2^T const frags,
// B = alpha bf16 K-pairs; C row 4q+r lands on the lane that packs slot
// (tag 16c+4q+r) next step. Emissions exp2'd once into flexp[256][52]
// (+16 guard), pads exactly 0; per-step eh = 4 broadcast ds_read_b128.

#define TAGS 50
#define LEN 256
#define NB 256
#define RSTRIDE 52
#define INV_LN2 1.4426950408889634f
#define LN2 0.6931471805599453f

typedef __attribute__((ext_vector_type(8))) short bf16x8;
typedef __attribute__((ext_vector_type(4))) float f32x4;

#if __has_builtin(__builtin_amdgcn_exp2f)
#define EXP2F(x) __builtin_amdgcn_exp2f(x)
#else
#define EXP2F(x) exp2f(x)
#endif
#if __has_builtin(__builtin_amdgcn_logf)
#define LOG2F(x) __builtin_amdgcn_logf(x)
#else
#define LOG2F(x) log2f(x)
#endif
#if __has_builtin(__builtin_amdgcn_rcpf)
#define RCPF(x) __builtin_amdgcn_rcpf(x)
#else
#define RCPF(x) (1.0f / (x))
#endif

__device__ __forceinline__ float readlane_f(float v, int srclane) {
  return __builtin_bit_cast(float,
      __builtin_amdgcn_readlane(__builtin_bit_cast(int, v), srclane));
}

// Pack two fp32 into one VGPR as (bf16(hi) << 16) | bf16(lo), round-half-up.
__device__ __forceinline__ int bf16pair(float lo, float hi) {
  unsigned lb = (__builtin_bit_cast(unsigned, lo) + 0x8000u) >> 16;
  unsigned hb = (__builtin_bit_cast(unsigned, hi) + 0x8000u) & 0xFFFF0000u;
  return (int)(hb | lb);
}

union U8 { int i[4]; bf16x8 v; };

__global__ __launch_bounds__(64, 1) void crf_fused_kernel(
    const float* __restrict__ feats,   // (B, L, T)
    const float* __restrict__ trans,   // (T, T)
    const int*   __restrict__ tags,    // (B, L)
    const int*   __restrict__ mask,    // (B, L)
    float*       __restrict__ out)     // (B,)
{
  const int b    = blockIdx.x;
  const int lane = threadIdx.x;
  const int q    = lane >> 4;
  const int n    = lane & 15;

  __shared__ __align__(16) float flexp[LEN * RSTRIDE + 16]; // exp2(feat/ln2), pads 0
  __shared__ int ml[LEN];
  __shared__ int tl[LEN];

  // ---- Preload: feats -> exp2 table (scatter via magic /50), masks, tags ----
  {
    const float4* fv = (const float4*)(feats + (size_t)b * LEN * TAGS);
    for (int i4 = lane; i4 < (LEN * TAGS) / 4; i4 += 64) {
      float4 v4 = fv[i4];
      float vv[4] = {v4.x, v4.y, v4.z, v4.w};
      const int base = i4 * 4;
#pragma unroll
      for (int e = 0; e < 4; ++e) {
        const int idx = base + e;
        const unsigned row =
            (unsigned)(((unsigned long long)(unsigned)idx * 1374389535ull) >> 36);
        const int col = idx - (int)row * 50;
        flexp[row * RSTRIDE + col] = EXP2F(vv[e] * INV_LN2);
      }
    }
    for (int i = lane; i < LEN; i += 64) {
      flexp[i * RSTRIDE + 50] = 0.0f;
      flexp[i * RSTRIDE + 51] = 0.0f;
      ml[i] = mask[b * LEN + i];
      tl[i] = tags[b * LEN + i];
    }
    if (lane < 16) flexp[LEN * RSTRIDE + lane] = 0.0f;
  }
  __syncthreads();

  // ---- Constant A-frags: Af = E2^T (fwd), Ab = E2 (bwd). R11-verified
  //      layout: A row = n, K-slot permutation by own q. Pads (row/tag>=50)=0.
  U8 Af[4][2], Ab[4][2];
#pragma unroll
  for (int t = 0; t < 4; ++t)
#pragma unroll
    for (int c = 0; c < 2; ++c)
#pragma unroll
      for (int r = 0; r < 4; ++r) {
        const int col = 16 * t + n;
        const int tag0 = 16 * c + 4 * q + r;
        const int tag1 = tag0 + 32;
        float f0 = 0.0f, f1 = 0.0f, g0 = 0.0f, g1 = 0.0f;
        if (col < TAGS) {
          if (tag0 < TAGS) {
            f0 = EXP2F(trans[tag0 * TAGS + col] * INV_LN2);
            g0 = EXP2F(trans[col * TAGS + tag0] * INV_LN2);
          }
          if (tag1 < TAGS) {
            f1 = EXP2F(trans[tag1 * TAGS + col] * INV_LN2);
            g1 = EXP2F(trans[col * TAGS + tag1] * INV_LN2);
          }
        }
        Af[t][c].i[r] = bf16pair(f0, f1);
        Ab[t][c].i[r] = bf16pair(g0, g1);
      }

  const f32x4 zero4 = {0.0f, 0.0f, 0.0f, 0.0f};

#define LDEH(l_, I_) (*(const f32x4*)&flexp[(l_) * RSTRIDE + 16 * (I_) + 4 * q])

  // State: vaf/vab [4I+r] = alpha[16I+4q+r] * 2^-S (replicated over n).
  float vaf[16], vab[16], Sf, Sb;

  {  // fwd init at l=0 (pivot = flexp[0][0])
    const float r0 = RCPF(flexp[0]);
    f32x4 i0 = LDEH(0, 0), i1 = LDEH(0, 1), i2 = LDEH(0, 2), i3 = LDEH(0, 3);
#pragma unroll
    for (int r = 0; r < 4; ++r) {
      vaf[r]      = i0[r] * r0;
      vaf[4 + r]  = i1[r] * r0;
      vaf[8 + r]  = i2[r] * r0;
      vaf[12 + r] = (48 + 4 * q + r < TAGS) ? i3[r] * r0 : 0.0f;
    }
    Sf = LOG2F(flexp[0]);
  }
#pragma unroll
  for (int r = 0; r < 4; ++r) {  // bwd init: ones (pads 0)
    vab[r] = 1.0f; vab[4 + r] = 1.0f; vab[8 + r] = 1.0f;
    vab[12 + r] = (48 + 4 * q + r < TAGS) ? 1.0f : 0.0f;
  }
  Sb = 0.0f;

  f32x4 ehf0 = LDEH(1, 0), ehf1 = LDEH(1, 1), ehf2 = LDEH(1, 2), ehf3 = LDEH(1, 3);
  f32x4 ehb0 = LDEH(255, 0), ehb1 = LDEH(255, 1), ehb2 = LDEH(255, 2), ehb3 = LDEH(255, 3);
  int mf = ml[1], mb = ml[255];

  // ---- Main loop: 127 fused iterations (fwd lf=k+1, bwd lb=255-k) ----
  for (int k = 0; k < 127; ++k) {
    const int lfn = (k + 2 < 128) ? (k + 2) : 127;
    const int lbn = 254 - k;  // >= 128 for k <= 126

    // fwd: pack alpha, 8 independent MFMAs
    const float ccf = readlane_f(vaf[0], 0);
    const float rrf = RCPF(ccf);
    U8 F0, F1;
#pragma unroll
    for (int r = 0; r < 4; ++r) {
      F0.i[r] = bf16pair(vaf[r],     vaf[8 + r]);
      F1.i[r] = bf16pair(vaf[4 + r], vaf[12 + r]);
    }
    f32x4 fa0 = __builtin_amdgcn_mfma_f32_16x16x32_bf16(Af[0][0].v, F0.v, zero4, 0, 0, 0);
    f32x4 fa1 = __builtin_amdgcn_mfma_f32_16x16x32_bf16(Af[1][0].v, F0.v, zero4, 0, 0, 0);
    f32x4 fa2 = __builtin_amdgcn_mfma_f32_16x16x32_bf16(Af[2][0].v, F0.v, zero4, 0, 0, 0);
    f32x4 fa3 = __builtin_amdgcn_mfma_f32_16x16x32_bf16(Af[3][0].v, F0.v, zero4, 0, 0, 0);
    f32x4 fb0 = __builtin_amdgcn_mfma_f32_16x16x32_bf16(Af[0][1].v, F1.v, zero4, 0, 0, 0);
    f32x4 fb1 = __builtin_amdgcn_mfma_f32_16x16x32_bf16(Af[1][1].v, F1.v, zero4, 0, 0, 0);
    f32x4 fb2 = __builtin_amdgcn_mfma_f32_16x16x32_bf16(Af[2][1].v, F1.v, zero4, 0, 0, 0);
    f32x4 fb3 = __builtin_amdgcn_mfma_f32_16x16x32_bf16(Af[3][1].v, F1.v, zero4, 0, 0, 0);

    // bwd: x = eh .* w, pack, 8 independent MFMAs
    const float ccb = readlane_f(vab[0], 0);
    const float rrb = RCPF(ccb);
    float x[16];
#pragma unroll
    for (int r = 0; r < 4; ++r) {
      x[r]      = vab[r]      * ehb0[r];
      x[4 + r]  = vab[4 + r]  * ehb1[r];
      x[8 + r]  = vab[8 + r]  * ehb2[r];
      x[12 + r] = vab[12 + r] * ehb3[r];
    }
    U8 G0, G1;
#pragma unroll
    for (int r = 0; r < 4; ++r) {
      G0.i[r] = bf16pair(x[r],     x[8 + r]);
      G1.i[r] = bf16pair(x[4 + r], x[12 + r]);
    }
    f32x4 ba0 = __builtin_amdgcn_mfma_f32_16x16x32_bf16(Ab[0][0].v, G0.v, zero4, 0, 0, 0);
    f32x4 ba1 = __builtin_amdgcn_mfma_f32_16x16x32_bf16(Ab[1][0].v, G0.v, zero4, 0, 0, 0);
    f32x4 ba2 = __builtin_amdgcn_mfma_f32_16x16x32_bf16(Ab[2][0].v, G0.v, zero4, 0, 0, 0);
    f32x4 ba3 = __builtin_amdgcn_mfma_f32_16x16x32_bf16(Ab[3][0].v, G0.v, zero4, 0, 0, 0);
    f32x4 bb0 = __builtin_amdgcn_mfma_f32_16x16x32_bf16(Ab[0][1].v, G1.v, zero4, 0, 0, 0);
    f32x4 bb1 = __builtin_amdgcn_mfma_f32_16x16x32_bf16(Ab[1][1].v, G1.v, zero4, 0, 0, 0);
    f32x4 bb2 = __builtin_amdgcn_mfma_f32_16x16x32_bf16(Ab[2][1].v, G1.v, zero4, 0, 0, 0);
    f32x4 bb3 = __builtin_amdgcn_mfma_f32_16x16x32_bf16(Ab[3][1].v, G1.v, zero4, 0, 0, 0);

    // prefetch next eh rows + masks (hidden under MFMAs)
    f32x4 nf0 = LDEH(lfn, 0), nf1 = LDEH(lfn, 1), nf2 = LDEH(lfn, 2), nf3 = LDEH(lfn, 3);
    f32x4 nb0 = LDEH(lbn, 0), nb1 = LDEH(lbn, 1), nb2 = LDEH(lbn, 2), nb3 = LDEH(lbn, 3);
    const int mfn = ml[lfn], mbn = ml[lbn];

#pragma unroll
    for (int r = 0; r < 4; ++r) {
      vaf[r]      = ((mf > 0) ? (fa0[r] + fb0[r]) * ehf0[r] : vaf[r])      * rrf;
      vaf[4 + r]  = ((mf > 0) ? (fa1[r] + fb1[r]) * ehf1[r] : vaf[4 + r])  * rrf;
      vaf[8 + r]  = ((mf > 0) ? (fa2[r] + fb2[r]) * ehf2[r] : vaf[8 + r])  * rrf;
      vaf[12 + r] = ((mf > 0) ? (fa3[r] + fb3[r]) * ehf3[r] : vaf[12 + r]) * rrf;
      vab[r]      = ((mb > 0) ? (ba0[r] + bb0[r]) : vab[r])      * rrb;
      vab[4 + r]  = ((mb > 0) ? (ba1[r] + bb1[r]) : vab[4 + r])  * rrb;
      vab[8 + r]  = ((mb > 0) ? (ba2[r] + bb2[r]) : vab[8 + r])  * rrb;
      vab[12 + r] = ((mb > 0) ? (ba3[r] + bb3[r]) : vab[12 + r]) * rrb;
    }
    Sf += LOG2F(ccf);
    Sb += LOG2F(ccb);
    ehf0 = nf0; ehf1 = nf1; ehf2 = nf2; ehf3 = nf3;
    ehb0 = nb0; ehb1 = nb1; ehb2 = nb2; ehb3 = nb3;
    mf = mfn; mb = mbn;
  }

  // ---- Peeled final bwd step (lb = 128; ehb holds row 128, mb = ml[128]) ----
  {
    const float ccb = readlane_f(vab[0], 0);
    const float rrb = RCPF(ccb);
    float x[16];
#pragma unroll
    for (int r = 0; r < 4; ++r) {
      x[r]      = vab[r]      * ehb0[r];
      x[4 + r]  = vab[4 + r]  * ehb1[r];
      x[8 + r]  = vab[8 + r]  * ehb2[r];
      x[12 + r] = vab[12 + r] * ehb3[r];
    }
    U8 G0, G1;
#pragma unroll
    for (int r = 0; r < 4; ++r) {
      G0.i[r] = bf16pair(x[r],     x[8 + r]);
      G1.i[r] = bf16pair(x[4 + r], x[12 + r]);
    }
    f32x4 ba0 = __builtin_amdgcn_mfma_f32_16x16x32_bf16(Ab[0][0].v, G0.v, zero4, 0, 0, 0);
    f32x4 ba1 = __builtin_amdgcn_mfma_f32_16x16x32_bf16(Ab[1][0].v, G0.v, zero4, 0, 0, 0);
    f32x4 ba2 = __builtin_amdgcn_mfma_f32_16x16x32_bf16(Ab[2][0].v, G0.v, zero4, 0, 0, 0);
    f32x4 ba3 = __builtin_amdgcn_mfma_f32_16x16x32_bf16(Ab[3][0].v, G0.v, zero4, 0, 0, 0);
    f32x4 bb0 = __builtin_amdgcn_mfma_f32_16x16x32_bf16(Ab[0][1].v, G1.v, zero4, 0, 0, 0);
    f32x4 bb1 = __builtin_amdgcn_mfma_f32_16x16x32_bf16(Ab[1][1].v, G1.v, zero4, 0, 0, 0);
    f32x4 bb2 = __builtin_amdgcn_mfma_f32_16x16x32_bf16(Ab[2][1].v, G1.v, zero4, 0, 0, 0);
    f32x4 bb3 = __builtin_amdgcn_mfma_f32_16x16x32_bf16(Ab[3][1].v, G1.v, zero4, 0, 0, 0);
#pragma unroll
    for (int r = 0; r < 4; ++r) {
      vab[r]      = ((mb > 0) ? (ba0[r] + bb0[r]) : vab[r])      * rrb;
      vab[4 + r]  = ((mb > 0) ? (ba1[r] + bb1[r]) : vab[4 + r])  * rrb;
      vab[8 + r]  = ((mb > 0) ? (ba2[r] + bb2[r]) : vab[8 + r])  * rrb;
      vab[12 + r] = ((mb > 0) ? (ba3[r] + bb3[r]) : vab[12 + r]) * rrb;
    }
    Sb += LOG2F(ccb);
  }

  // ---- Fused combine: normalizer + gold -> out[b] ----
  // dot: tags partitioned by q (16 per q, replicated over n) -> reduce over q.
  float part = 0.0f;
#pragma unroll
  for (int i = 0; i < 16; ++i) part += vaf[i] * vab[i];
  part += __shfl_xor(part, 16, 64);
  part += __shfl_xor(part, 32, 64);

  // gold: feat recovered as ln2*log2(flexp); trans gathered from L2.
  float gp = 0.0f;
#pragma unroll
  for (int kk = 0; kk < 4; ++kk) {
    const int p = lane + 64 * kk;
    const int tg = tl[p];
    if (ml[p] > 0) {
      float vv = LN2 * LOG2F(flexp[p * RSTRIDE + tg]);
      if (p >= 1) vv += trans[tl[p - 1] * TAGS + tg];
      gp += vv;
    }
  }
#pragma unroll
  for (int off = 32; off; off >>= 1) gp += __shfl_xor(gp, off, 64);

  if (lane == 0) out[b] = LN2 * (Sf + Sb + LOG2F(part)) - gp;
#undef LDEH
}

extern "C" void kernel_launch(void* const* d_in, const int* in_sizes, int n_in,
                              void* d_out, int out_size, void* d_ws, size_t ws_size,
                              hipStream_t stream) {
  const float* feats = (const float*)d_in[0];
  const float* trans = (const float*)d_in[1];
  const int*   tags  = (const int*)d_in[2];
  const int*   mask  = (const int*)d_in[3];
  float* out = (float*)d_out;
  (void)d_ws; (void)ws_size;

  crf_fused_kernel<<<NB, 64, 0, stream>>>(feats, trans, tags, mask, out);
}

// Round 3
// 106.352 us; speedup vs baseline: 1.4520x; 1.4520x over previous
//
#include <hip/hip_runtime.h>
#include <math.h>

// CRF loss: B=256, L=256, T=50.
// R13: kill the ~830cy/step FIXED cost identified from R10/R11/R12 scaling
//   (cost = 830cy + 1.3cy/VALU per step; R12's 2-chains-in-1-wave gave an
//   exact 2x -> the stall is per-step serialized latency, not VALU issue).
//   Back on R10's split grid (512 blocks x 1 wave: fwd | bwd, + combine).
//   Fixes:
//   1. eh double-buffer (banks eA/eB, reload right after last use, consumed
//      2 steps later) -> no eh=nf copies, LDS latency covered by 2 steps.
//   2. Renorm every 4 steps (quad top). Drift bound ~2^80 << 2^127 range of
//      bf16/f32; S += log2(cc) at renorms only; u,w stay value*2^S.
//   3. v_cvt_pk_bf16_f32 (1 inst) replaces 5-inst hand bf16 pack.
//   4. Mask via wave ballot in SGPRs (SALU bit test + uniform branch), no
//      per-step LDS mask read, no cndmasks.
//   5. Chained MFMA pairs (4 independent 2-chains).
// Recurrence = R11/R12-verified lane-local form: A-frags = E2^T (fwd) /
// E2 (bwd), B = alpha bf16 K-pairs, C row 16I+4q+r lands on the lane that
// packs slot (tag 16c+4q+r). Pad tags (>=50) stay exactly 0 end-to-end:
// A-frag pad rows/cols are 0 -> MFMA pad-row outputs are 0 -> out-of-row
// eh reads (RS=52 quirk) multiply structurally-zero state (R12-proven).

#define TAGS 50
#define LEN 256
#define NB 256
#define HALF 128
#define RS 52
#define INV_LN2 1.4426950408889634f
#define LN2 0.6931471805599453f

typedef __attribute__((ext_vector_type(8))) short bf16x8;
typedef __attribute__((ext_vector_type(4))) float f32x4;

#if __has_builtin(__builtin_amdgcn_exp2f)
#define EXP2F(x) __builtin_amdgcn_exp2f(x)
#else
#define EXP2F(x) exp2f(x)
#endif
#if __has_builtin(__builtin_amdgcn_logf)
#define LOG2F(x) __builtin_amdgcn_logf(x)
#else
#define LOG2F(x) log2f(x)
#endif
#if __has_builtin(__builtin_amdgcn_rcpf)
#define RCPF(x) __builtin_amdgcn_rcpf(x)
#else
#define RCPF(x) (1.0f / (x))
#endif

__device__ __forceinline__ float readlane_f(float v, int srclane) {
  return __builtin_bit_cast(float,
      __builtin_amdgcn_readlane(__builtin_bit_cast(int, v), srclane));
}

__device__ __forceinline__ int bf16pairInit(float lo, float hi) {
  unsigned lb = (__builtin_bit_cast(unsigned, lo) + 0x8000u) >> 16;
  unsigned hb = (__builtin_bit_cast(unsigned, hi) + 0x8000u) & 0xFFFF0000u;
  return (int)(hb | lb);
}

// One-instruction pack: dst = (bf16(hi)<<16) | bf16(lo), RNE.
#define PACK2(dst, lo, hi) \
  asm("v_cvt_pk_bf16_f32 %0, %1, %2" : "=v"(dst) : "v"(lo), "v"(hi))

union U8 { int i[4]; bf16x8 v; };

// ws layout (floats): u[NB][64] | w[NB][64] | Sf[NB] | Sb[NB]
#define WS_U(b)  ((b) * 64)
#define WS_W(b)  ((NB + (b)) * 64)
#define WS_SF(b) (2 * NB * 64 + (b))
#define WS_SB(b) (2 * NB * 64 + NB + (b))

__global__ __launch_bounds__(64) void crf_scan_kernel(
    const float* __restrict__ feats,   // (B, L, T)
    const float* __restrict__ trans,   // (T, T)
    const int*   __restrict__ mask,    // (B, L)
    float*       __restrict__ ws)
{
  const int bid    = blockIdx.x;
  const bool is_fwd = bid < NB;
  const int b      = is_fwd ? bid : bid - NB;
  const int lane   = threadIdx.x;
  const int q      = lane >> 4;
  const int n      = lane & 15;

  __shared__ __align__(16) float flexp[HALF * RS + 16];  // exp2(feat/ln2)

  const int base_l = is_fwd ? 0 : HALF;
  const float* fb = feats + ((size_t)b * LEN + base_l) * TAGS;
  const int*   mb = mask + b * LEN + base_l;

  // ---- Preload: feats -> exp2 table (scatter via magic /50) ----
  {
    const float4* fv = (const float4*)fb;
    for (int i4 = lane; i4 < (HALF * TAGS) / 4; i4 += 64) {
      float4 v4 = fv[i4];
      float vv[4] = {v4.x, v4.y, v4.z, v4.w};
      const int base = i4 * 4;
#pragma unroll
      for (int e = 0; e < 4; ++e) {
        const int idx = base + e;
        const unsigned row =
            (unsigned)(((unsigned long long)(unsigned)idx * 1374389535ull) >> 36);
        const int col = idx - (int)row * 50;
        flexp[row * RS + col] = EXP2F(vv[e] * INV_LN2);
      }
    }
    for (int i = lane; i < HALF; i += 64) {
      flexp[i * RS + 50] = 0.0f;
      flexp[i * RS + 51] = 0.0f;
    }
    if (lane < 16) flexp[HALF * RS + lane] = 0.0f;
  }
  // Mask bits for this half as wave-uniform 64-bit ballots (SGPRs).
  const unsigned long long mball0 = __ballot(mb[lane] > 0);
  const unsigned long long mball1 = __ballot(mb[64 + lane] > 0);
  __syncthreads();

  // ---- Constant A-frags (R11-verified layout; pads exactly 0) ----
  U8 Afr[4][2];
#pragma unroll
  for (int t = 0; t < 4; ++t)
#pragma unroll
    for (int c = 0; c < 2; ++c)
#pragma unroll
      for (int r = 0; r < 4; ++r) {
        const int col = 16 * t + n;
        const int tag0 = 16 * c + 4 * q + r;
        const int tag1 = tag0 + 32;
        float e0 = 0.0f, e1 = 0.0f;
        if (col < TAGS) {
          if (tag0 < TAGS)
            e0 = EXP2F((is_fwd ? trans[tag0 * TAGS + col]
                               : trans[col * TAGS + tag0]) * INV_LN2);
          if (tag1 < TAGS)
            e1 = EXP2F((is_fwd ? trans[tag1 * TAGS + col]
                               : trans[col * TAGS + tag1]) * INV_LN2);
        }
        Afr[t][c].i[r] = bf16pairInit(e0, e1);
      }

  const f32x4 zero4 = {0.0f, 0.0f, 0.0f, 0.0f};

  float va[16];  // va[4I+r] = state[16I+4q+r] (x 2^-S), replicated over n
  float S = 0.0f;
  f32x4 eA[4], eB[4];

#define MASKBIT(L) \
  ((int)(((((L) & 64) ? mball1 : mball0) >> ((L) & 63)) & 1ull))

#define LOAD4(BK, ROW) do {                                   \
    const float* _p = &flexp[(ROW) * RS + 4 * q];             \
    BK[0] = *(const f32x4*)(_p);                              \
    BK[1] = *(const f32x4*)(_p + 16);                         \
    BK[2] = *(const f32x4*)(_p + 32);                         \
    BK[3] = *(const f32x4*)(_p + 48);                         \
  } while (0)

#define RENORM() do {                                         \
    const float _cc = readlane_f(va[0], 0);                   \
    const float _rr = RCPF(_cc);                              \
    S += LOG2F(_cc);                                          \
    _Pragma("unroll") for (int _i = 0; _i < 16; ++_i) va[_i] *= _rr; \
  } while (0)

#define MFMA8(B0_, B1_)                                                        \
    f32x4 d0 = __builtin_amdgcn_mfma_f32_16x16x32_bf16(Afr[0][1].v, B1_.v, zero4, 0, 0, 0); \
    f32x4 d1 = __builtin_amdgcn_mfma_f32_16x16x32_bf16(Afr[1][1].v, B1_.v, zero4, 0, 0, 0); \
    f32x4 d2 = __builtin_amdgcn_mfma_f32_16x16x32_bf16(Afr[2][1].v, B1_.v, zero4, 0, 0, 0); \
    f32x4 d3 = __builtin_amdgcn_mfma_f32_16x16x32_bf16(Afr[3][1].v, B1_.v, zero4, 0, 0, 0); \
    d0 = __builtin_amdgcn_mfma_f32_16x16x32_bf16(Afr[0][0].v, B0_.v, d0, 0, 0, 0);          \
    d1 = __builtin_amdgcn_mfma_f32_16x16x32_bf16(Afr[1][0].v, B0_.v, d1, 0, 0, 0);          \
    d2 = __builtin_amdgcn_mfma_f32_16x16x32_bf16(Afr[2][0].v, B0_.v, d2, 0, 0, 0);          \
    d3 = __builtin_amdgcn_mfma_f32_16x16x32_bf16(Afr[3][0].v, B0_.v, d3, 0, 0, 0)

#define FSTEP(EH, L, RL) do {                                 \
    if (MASKBIT(L)) {                                         \
      U8 B0, B1;                                              \
      PACK2(B0.i[0], va[0], va[8]);                           \
      PACK2(B0.i[1], va[1], va[9]);                           \
      PACK2(B0.i[2], va[2], va[10]);                          \
      PACK2(B0.i[3], va[3], va[11]);                          \
      PACK2(B1.i[0], va[4], va[12]);                          \
      PACK2(B1.i[1], va[5], va[13]);                          \
      PACK2(B1.i[2], va[6], va[14]);                          \
      PACK2(B1.i[3], va[7], va[15]);                          \
      MFMA8(B0, B1);                                          \
      _Pragma("unroll") for (int _r = 0; _r < 4; ++_r) {      \
        va[_r]      = d0[_r] * EH[0][_r];                     \
        va[4 + _r]  = d1[_r] * EH[1][_r];                     \
        va[8 + _r]  = d2[_r] * EH[2][_r];                     \
        va[12 + _r] = d3[_r] * EH[3][_r];                     \
      }                                                       \
    }                                                         \
    LOAD4(EH, RL);                                            \
  } while (0)

#define BSTEP(EH, L, RL) do {                                 \
    if (MASKBIT(L)) {                                         \
      float x[16];                                            \
      _Pragma("unroll") for (int _r = 0; _r < 4; ++_r) {      \
        x[_r]      = va[_r]      * EH[0][_r];                 \
        x[4 + _r]  = va[4 + _r]  * EH[1][_r];                 \
        x[8 + _r]  = va[8 + _r]  * EH[2][_r];                 \
        x[12 + _r] = va[12 + _r] * EH[3][_r];                 \
      }                                                       \
      U8 B0, B1;                                              \
      PACK2(B0.i[0], x[0], x[8]);                             \
      PACK2(B0.i[1], x[1], x[9]);                             \
      PACK2(B0.i[2], x[2], x[10]);                            \
      PACK2(B0.i[3], x[3], x[11]);                            \
      PACK2(B1.i[0], x[4], x[12]);                            \
      PACK2(B1.i[1], x[5], x[13]);                            \
      PACK2(B1.i[2], x[6], x[14]);                            \
      PACK2(B1.i[3], x[7], x[15]);                            \
      MFMA8(B0, B1);                                          \
      _Pragma("unroll") for (int _r = 0; _r < 4; ++_r) {      \
        va[_r]      = d0[_r];                                 \
        va[4 + _r]  = d1[_r];                                 \
        va[8 + _r]  = d2[_r];                                 \
        va[12 + _r] = d3[_r];                                 \
      }                                                       \
    }                                                         \
    LOAD4(EH, RL);                                            \
  } while (0)

  if (is_fwd) {
    // ---- init: va = raw row0 (first RENORM normalizes; S starts 0) ----
    LOAD4(eA, 0);
#pragma unroll
    for (int r = 0; r < 4; ++r) {
      va[r]      = eA[0][r];
      va[4 + r]  = eA[1][r];
      va[8 + r]  = eA[2][r];
      va[12 + r] = (48 + 4 * q + r < TAGS) ? eA[3][r] : 0.0f;
    }
    LOAD4(eA, 1);
    LOAD4(eB, 2);

    for (int k = 0; k < 31; ++k) {
      const int l0 = 4 * k + 1;          // steps l0..l0+3 (1..124)
      RENORM();
      FSTEP(eA, l0,     l0 + 2);
      FSTEP(eB, l0 + 1, l0 + 3);
      FSTEP(eA, l0 + 2, l0 + 4);
      FSTEP(eB, l0 + 3, l0 + 5);         // max row 126
    }
    RENORM();                            // tail: l = 125,126,127
    FSTEP(eA, 125, 127);
    FSTEP(eB, 126, 127);
    FSTEP(eA, 127, 127);

    if (n == 0) {
#pragma unroll
      for (int I = 0; I < 4; ++I)
#pragma unroll
        for (int r = 0; r < 4; ++r)
          ws[WS_U(b) + 16 * I + 4 * q + r] = va[4 * I + r];
    }
    if (lane == 0) ws[WS_SF(b)] = S;
  } else {
    // ---- init: ones (pads 0) ----
#pragma unroll
    for (int r = 0; r < 4; ++r) {
      va[r] = 1.0f; va[4 + r] = 1.0f; va[8 + r] = 1.0f;
      va[12 + r] = (48 + 4 * q + r < TAGS) ? 1.0f : 0.0f;
    }
    LOAD4(eA, 127);
    LOAD4(eB, 126);

    for (int k = 0; k < 32; ++k) {
      const int l0 = 127 - 4 * k;        // steps l0..l0-3 (127..0)
      RENORM();
      BSTEP(eA, l0,     (l0 - 2 >= 0) ? l0 - 2 : 0);
      BSTEP(eB, l0 - 1, (l0 - 3 >= 0) ? l0 - 3 : 0);
      BSTEP(eA, l0 - 2, (l0 - 4 >= 0) ? l0 - 4 : 0);
      BSTEP(eB, l0 - 3, (l0 - 5 >= 0) ? l0 - 5 : 0);
    }

    if (n == 0) {
#pragma unroll
      for (int I = 0; I < 4; ++I)
#pragma unroll
        for (int r = 0; r < 4; ++r)
          ws[WS_W(b) + 16 * I + 4 * q + r] = va[4 * I + r];
    }
    if (lane == 0) ws[WS_SB(b)] = S;
  }
#undef MASKBIT
#undef LOAD4
#undef RENORM
#undef MFMA8
#undef FSTEP
#undef BSTEP
}

__global__ __launch_bounds__(64) void crf_combine_kernel(
    const float* __restrict__ feats,   // (B, L, T)
    const float* __restrict__ trans,   // (T, T)
    const int*   __restrict__ tags,    // (B, L)
    const int*   __restrict__ mask,    // (B, L)
    const float* __restrict__ ws,
    float*       __restrict__ out)     // (B,)
{
  const int b = blockIdx.x;
  const int lane = threadIdx.x;

  // normalizer = ln2 * (Sf + Sb + log2(sum_tag u*w))   (pads are 0)
  float s = ws[WS_U(b) + lane] * ws[WS_W(b) + lane];
#pragma unroll
  for (int off = 32; off; off >>= 1) s += __shfl_xor(s, off, 64);

  // gold score: lane handles positions lane, +64, +128, +192
  const float* fb = feats + (size_t)b * (LEN * TAGS);
  const int*   tb = tags + b * LEN;
  const int*   mb = mask + b * LEN;
  float gp = 0.0f;
#pragma unroll
  for (int k = 0; k < 4; ++k) {
    const int p = lane + 64 * k;
    const int tg = tb[p];
    if (mb[p] > 0) {
      float vv = fb[p * TAGS + tg];
      if (p >= 1) vv += trans[tb[p - 1] * TAGS + tg];
      gp += vv;
    }
  }
#pragma unroll
  for (int off = 32; off; off >>= 1) gp += __shfl_xor(gp, off, 64);

  if (lane == 0) {
    const float Sf = ws[WS_SF(b)];
    const float Sb = ws[WS_SB(b)];
    out[b] = LN2 * (Sf + Sb + LOG2F(s)) - gp;
  }
}

extern "C" void kernel_launch(void* const* d_in, const int* in_sizes, int n_in,
                              void* d_out, int out_size, void* d_ws, size_t ws_size,
                              hipStream_t stream) {
  const float* feats = (const float*)d_in[0];
  const float* trans = (const float*)d_in[1];
  const int*   tags  = (const int*)d_in[2];
  const int*   mask  = (const int*)d_in[3];
  float* out = (float*)d_out;
  float* ws  = (float*)d_ws;   // needs (2*256*64 + 512) * 4 = 133 KB

  crf_scan_kernel<<<2 * NB, 64, 0, stream>>>(feats, trans, mask, ws);
  crf_combine_kernel<<<NB, 64, 0, stream>>>(feats, trans, tags, mask, ws, out);
}

// Round 4
// 106.125 us; speedup vs baseline: 1.4551x; 1.0021x over previous
//
#include <hip/hip_runtime.h>
#include <math.h>

// CRF loss: B=256, L=256, T=50.
// R14: SEGMENTED matrix scan — cut serial depth 128->32, waves 512->2048.
//   R10-R13 established: per-step cost ~840cy is a fixed whole-wave stall
//   (R12: two chains in one wave = exact 2x -> no intra-wave overlap;
//   R13: removing 60% of VALU moved cost only ~8%). So: fewer serial steps
//   + more waves is the only lever left.
//   Block b (512 thr = 8 waves) handles batch b. Wave w computes segment
//   P_w = prod of M_l over l in [32w+1 .. 32w+32] (w=7: ..255) as a full
//   64x64 (padded 50x50) matrix chain: P <- P.M_l = (P.E2) col-scaled by
//   eh_l. Same verified A=E2^T fragments; B now carries 16 DISTINCT rows
//   of P per row-block J (B col = lane&15, mirroring the verified A row =
//   lane&15). Output slot d[J][I][r] = P[16J+n][16I+4q+r] is exactly the
//   slot the next step's B-pack needs -> still 100% lane-local, 32 MFMAs
//   per step in 16 independent chains.
//   Epilogue: wave0 folds u = v0.P0 in-register; wave7 folds w = P7.1
//   (row sums); waves1-6 store P-hat bf16 to LDS (48KB); barrier; wave0
//   runs the 6-matvec x-chain in fp32 + dot(x,w); wave1 computes gold;
//   out[b] = ln2*(sum S + log2(dot)) - gold. One kernel, no workspace.
//   eh rows stream from GLOBAL (no flexp staging): 4x dwordx4 per step,
//   double-buffered 2 steps ahead; the I=3 load is taken at col offset 46
//   (clamped to buffer end) so the last row never reads OOB; cols >=50 are
//   structurally zero (E2 pad cols) so junk lanes multiply 0.

#define TAGS 50
#define LEN 256
#define NB 256
#define TOTF (NB * LEN * TAGS)
#define INV_LN2 1.4426950408889634f
#define LN2 0.6931471805599453f

typedef __attribute__((ext_vector_type(8))) short bf16x8;
typedef __attribute__((ext_vector_type(4))) float f32x4;
typedef __attribute__((ext_vector_type(4), aligned(4))) float f32x4u;

#if __has_builtin(__builtin_amdgcn_exp2f)
#define EXP2F(x) __builtin_amdgcn_exp2f(x)
#else
#define EXP2F(x) exp2f(x)
#endif
#if __has_builtin(__builtin_amdgcn_logf)
#define LOG2F(x) __builtin_amdgcn_logf(x)
#else
#define LOG2F(x) log2f(x)
#endif
#if __has_builtin(__builtin_amdgcn_rcpf)
#define RCPF(x) __builtin_amdgcn_rcpf(x)
#else
#define RCPF(x) (1.0f / (x))
#endif

__device__ __forceinline__ float readlane_f(float v, int srclane) {
  return __builtin_bit_cast(float,
      __builtin_amdgcn_readlane(__builtin_bit_cast(int, v), srclane));
}

__device__ __forceinline__ int bf16pairInit(float lo, float hi) {
  unsigned lb = (__builtin_bit_cast(unsigned, lo) + 0x8000u) >> 16;
  unsigned hb = (__builtin_bit_cast(unsigned, hi) + 0x8000u) & 0xFFFF0000u;
  return (int)(hb | lb);
}

__device__ __forceinline__ float bf16f(unsigned short u) {
  return __builtin_bit_cast(float, ((unsigned)u) << 16);
}

// One-instruction pack: dst = (bf16(hi)<<16) | bf16(lo), RNE.
#define PACK2(dst, lo, hi) \
  asm("v_cvt_pk_bf16_f32 %0, %1, %2" : "=v"(dst) : "v"(lo), "v"(hi))

union U8 { int i[4]; bf16x8 v; };

__global__ __launch_bounds__(512, 1) void crf_seg_kernel(
    const float* __restrict__ feats,   // (B, L, T)
    const float* __restrict__ trans,   // (T, T)
    const int*   __restrict__ tags,    // (B, L)
    const int*   __restrict__ mask,    // (B, L)
    float*       __restrict__ out)     // (B,)
{
  const int b    = blockIdx.x;
  const int tid  = threadIdx.x;
  const int w    = tid >> 6;
  const int lane = tid & 63;
  const int q    = lane >> 4;
  const int n    = lane & 15;

  __shared__ __align__(16) unsigned short Plds[6][64][64]; // P-hat 1..6, bf16
  __shared__ __align__(16) float u_lds[64];
  __shared__ __align__(16) float w_lds[64];
  __shared__ float Sseg[8];
  __shared__ float norm_s, gold_s;

  // ---- mask ballots (wave-uniform SGPRs) ----
  const int* mbp = mask + b * LEN;
  const unsigned long long mb0 = __ballot(mbp[lane] > 0);
  const unsigned long long mb1 = __ballot(mbp[64 + lane] > 0);
  const unsigned long long mb2 = __ballot(mbp[128 + lane] > 0);
  const unsigned long long mb3 = __ballot(mbp[192 + lane] > 0);
#define MASKBIT(L)                                                          \
  ((int)(((((L) & 128) ? (((L) & 64) ? mb3 : mb2)                           \
                       : (((L) & 64) ? mb1 : mb0)) >> ((L) & 63)) & 1ull))

  // ---- Constant A-frags = E2^T (fwd orientation), pads exactly 0 ----
  U8 Afr[4][2];
#pragma unroll
  for (int t = 0; t < 4; ++t)
#pragma unroll
    for (int c = 0; c < 2; ++c)
#pragma unroll
      for (int r = 0; r < 4; ++r) {
        const int col = 16 * t + n;
        const int tag0 = 16 * c + 4 * q + r;
        const int tag1 = tag0 + 32;
        float e0 = 0.0f, e1 = 0.0f;
        if (col < TAGS) {
          if (tag0 < TAGS) e0 = EXP2F(trans[tag0 * TAGS + col] * INV_LN2);
          if (tag1 < TAGS) e1 = EXP2F(trans[tag1 * TAGS + col] * INV_LN2);
        }
        Afr[t][c].i[r] = bf16pairInit(e0, e1);
      }

  const f32x4 zero4 = {0.0f, 0.0f, 0.0f, 0.0f};

  // State: d[J][I][r] = P[16J+n][16I+4q+r] * 2^-S.  Init P = I.
  f32x4 d[4][4];
#pragma unroll
  for (int J = 0; J < 4; ++J)
#pragma unroll
    for (int I = 0; I < 4; ++I)
#pragma unroll
      for (int r = 0; r < 4; ++r)
        d[J][I][r] = (16 * J + n == 16 * I + 4 * q + r) ? 1.0f : 0.0f;

  const int l0 = 32 * w + 1;
  float S = 0.0f;
  f32x4u rA[4], rB[4];

  // raw eh loads: cols [4q..], [16+4q..], [32+4q..], and [46+4q..] for I=3
  // (shifted so the absolute-last row stays in-bounds; real cols 48,49 land
  //  at elems 2,3; the rest of I=3 feeds structurally-zero columns).
#define LOADG(BK, L) do {                                                   \
    const float* _p = feats + (size_t)b * (LEN * TAGS) + (size_t)(L) * TAGS;\
    BK[0] = *(const f32x4u*)(_p + 4 * q);                                   \
    BK[1] = *(const f32x4u*)(_p + 16 + 4 * q);                              \
    BK[2] = *(const f32x4u*)(_p + 32 + 4 * q);                              \
    const float* _p3 = _p + 46 + 4 * q;                                     \
    const float* _lim = feats + (TOTF - 4);                                 \
    if (_p3 > _lim) _p3 = _lim;                                             \
    BK[3] = *(const f32x4u*)_p3;                                            \
  } while (0)

#define RENORMM() do {                                                      \
    const float _cc = readlane_f(d[0][0][0], 0);                            \
    const float _rr = RCPF(_cc);                                            \
    S += LOG2F(_cc);                                                        \
    _Pragma("unroll") for (int _J = 0; _J < 4; ++_J)                        \
    _Pragma("unroll") for (int _I = 0; _I < 4; ++_I)                        \
    _Pragma("unroll") for (int _r = 0; _r < 4; ++_r)                        \
      d[_J][_I][_r] *= _rr;                                                 \
  } while (0)

  // One matrix step: P <- (P.E2) col-scaled by exp2(eh_raw/ln2).
#define STEPM(EH, L) do {                                                   \
    if (MASKBIT(L)) {                                                       \
      float ev[4][4];                                                       \
      _Pragma("unroll") for (int _i = 0; _i < 3; ++_i)                      \
      _Pragma("unroll") for (int _r = 0; _r < 4; ++_r)                      \
        ev[_i][_r] = EXP2F(EH[_i][_r] * INV_LN2);                           \
      ev[3][0] = EXP2F(EH[3][2] * INV_LN2);                                 \
      ev[3][1] = EXP2F(EH[3][3] * INV_LN2);                                 \
      ev[3][2] = 0.0f; ev[3][3] = 0.0f;                                     \
      _Pragma("unroll") for (int _J = 0; _J < 4; ++_J) {                    \
        U8 B0, B1;                                                          \
        _Pragma("unroll") for (int _r = 0; _r < 4; ++_r) {                  \
          PACK2(B0.i[_r], d[_J][0][_r], d[_J][2][_r]);                      \
          PACK2(B1.i[_r], d[_J][1][_r], d[_J][3][_r]);                      \
        }                                                                   \
        f32x4 t0 = __builtin_amdgcn_mfma_f32_16x16x32_bf16(Afr[0][1].v, B1.v, zero4, 0, 0, 0); \
        f32x4 t1 = __builtin_amdgcn_mfma_f32_16x16x32_bf16(Afr[1][1].v, B1.v, zero4, 0, 0, 0); \
        f32x4 t2 = __builtin_amdgcn_mfma_f32_16x16x32_bf16(Afr[2][1].v, B1.v, zero4, 0, 0, 0); \
        f32x4 t3 = __builtin_amdgcn_mfma_f32_16x16x32_bf16(Afr[3][1].v, B1.v, zero4, 0, 0, 0); \
        t0 = __builtin_amdgcn_mfma_f32_16x16x32_bf16(Afr[0][0].v, B0.v, t0, 0, 0, 0); \
        t1 = __builtin_amdgcn_mfma_f32_16x16x32_bf16(Afr[1][0].v, B0.v, t1, 0, 0, 0); \
        t2 = __builtin_amdgcn_mfma_f32_16x16x32_bf16(Afr[2][0].v, B0.v, t2, 0, 0, 0); \
        t3 = __builtin_amdgcn_mfma_f32_16x16x32_bf16(Afr[3][0].v, B0.v, t3, 0, 0, 0); \
        _Pragma("unroll") for (int _r = 0; _r < 4; ++_r) {                  \
          d[_J][0][_r] = t0[_r] * ev[0][_r];                                \
          d[_J][1][_r] = t1[_r] * ev[1][_r];                                \
          d[_J][2][_r] = t2[_r] * ev[2][_r];                                \
          d[_J][3][_r] = t3[_r] * ev[3][_r];                                \
        }                                                                   \
      }                                                                     \
    }                                                                       \
  } while (0)

  // ---- Segment scan: 32 steps (w=7: 31), renorm every 4 ----
  LOADG(rA, l0);
  LOADG(rB, l0 + 1);

  for (int k = 0; k < 15; ++k) {
    const int l = l0 + 2 * k;
    if ((k & 1) == 0) RENORMM();
    STEPM(rA, l);
    { const int rl = (l + 2 < 255) ? l + 2 : 255; LOADG(rA, rl); }
    STEPM(rB, l + 1);
    { const int rl = (l + 3 < 255) ? l + 3 : 255; LOADG(rB, rl); }
  }
  STEPM(rA, l0 + 30);                 // s = 30 (all waves)
  if (w != 7) STEPM(rB, l0 + 31);     // s = 31 (waves 0..6 only)

  if (lane == 0) Sseg[w] = S;

  // ---- Per-wave epilogue ----
  if (w == 0) {
    // u = v0 . P-hat_0  (v0 = exp2(feats row 0 / ln2), pads 0)
    float v0v[4];
#pragma unroll
    for (int J = 0; J < 4; ++J) {
      const int tg = 16 * J + n;
      const float f = feats[(size_t)b * (LEN * TAGS) + tg];
      v0v[J] = (tg < TAGS) ? EXP2F(f * INV_LN2) : 0.0f;
    }
    float pu[4][4];
#pragma unroll
    for (int I = 0; I < 4; ++I)
#pragma unroll
      for (int r = 0; r < 4; ++r)
        pu[I][r] = v0v[0] * d[0][I][r] + v0v[1] * d[1][I][r] +
                   v0v[2] * d[2][I][r] + v0v[3] * d[3][I][r];
#pragma unroll
    for (int off = 1; off <= 8; off <<= 1)
#pragma unroll
      for (int I = 0; I < 4; ++I)
#pragma unroll
        for (int r = 0; r < 4; ++r)
          pu[I][r] += __shfl_xor(pu[I][r], off, 64);
    if (n == 0) {
#pragma unroll
      for (int I = 0; I < 4; ++I)
#pragma unroll
        for (int r = 0; r < 4; ++r)
          u_lds[16 * I + 4 * q + r] = pu[I][r];
    }
  } else if (w == 7) {
    // w-vec = P-hat_7 . 1  (row sums)
    float pw[4];
#pragma unroll
    for (int J = 0; J < 4; ++J) {
      float s = 0.0f;
#pragma unroll
      for (int I = 0; I < 4; ++I)
#pragma unroll
        for (int r = 0; r < 4; ++r)
          s += d[J][I][r];
      pw[J] = s;
    }
#pragma unroll
    for (int J = 0; J < 4; ++J) {
      pw[J] += __shfl_xor(pw[J], 16, 64);
      pw[J] += __shfl_xor(pw[J], 32, 64);
    }
    if (q == 0) {
#pragma unroll
      for (int J = 0; J < 4; ++J) w_lds[16 * J + n] = pw[J];
    }
  } else {
    // store P-hat bf16 (row-major [64][64])
#pragma unroll
    for (int J = 0; J < 4; ++J)
#pragma unroll
      for (int I = 0; I < 4; ++I) {
        int lo, hi;
        PACK2(lo, d[J][I][0], d[J][I][1]);
        PACK2(hi, d[J][I][2], d[J][I][3]);
        unsigned* dst = (unsigned*)&Plds[w - 1][16 * J + n][16 * I + 4 * q];
        dst[0] = (unsigned)lo;
        dst[1] = (unsigned)hi;
      }
  }

  __syncthreads();

  // ---- Combine (wave 0) and gold (wave 1), in parallel ----
  if (w == 0) {
    float x = u_lds[lane];   // col = lane
    float stot = 0.0f;
    for (int j = 0; j < 6; ++j) {
      u_lds[lane] = x;       // broadcast buffer (u consumed on j=0 entry)
      asm volatile("s_waitcnt lgkmcnt(0)" ::: "memory");
      float y0 = 0.0f, y1 = 0.0f, y2 = 0.0f, y3 = 0.0f;
#pragma unroll 4
      for (int r = 0; r < 64; r += 4) {
        y0 += u_lds[r]     * bf16f(Plds[j][r][lane]);
        y1 += u_lds[r + 1] * bf16f(Plds[j][r + 1][lane]);
        y2 += u_lds[r + 2] * bf16f(Plds[j][r + 2][lane]);
        y3 += u_lds[r + 3] * bf16f(Plds[j][r + 3][lane]);
      }
      float y = (y0 + y1) + (y2 + y3);
      const float cc = readlane_f(y, 0);
      stot += LOG2F(cc);
      x = y * RCPF(cc);
      asm volatile("s_waitcnt lgkmcnt(0)" ::: "memory");
    }
    float dotv = x * w_lds[lane];
#pragma unroll
    for (int off = 32; off; off >>= 1) dotv += __shfl_xor(dotv, off, 64);
    if (lane == 0) {
      float Ssum = 0.0f;
#pragma unroll
      for (int i = 0; i < 8; ++i) Ssum += Sseg[i];
      norm_s = LN2 * (Ssum + stot + LOG2F(dotv));
    }
  } else if (w == 1) {
    const float* fb = feats + (size_t)b * (LEN * TAGS);
    const int* tb = tags + b * LEN;
    float gp = 0.0f;
#pragma unroll
    for (int k = 0; k < 4; ++k) {
      const int p = lane + 64 * k;
      const int tg = tb[p];
      if (mbp[p] > 0) {
        float vv = fb[p * TAGS + tg];
        if (p >= 1) vv += trans[tb[p - 1] * TAGS + tg];
        gp += vv;
      }
    }
#pragma unroll
    for (int off = 32; off; off >>= 1) gp += __shfl_xor(gp, off, 64);
    if (lane == 0) gold_s = gp;
  }

  __syncthreads();
  if (tid == 0) out[b] = norm_s - gold_s;

#undef MASKBIT
#undef LOADG
#undef RENORMM
#undef STEPM
}

extern "C" void kernel_launch(void* const* d_in, const int* in_sizes, int n_in,
                              void* d_out, int out_size, void* d_ws, size_t ws_size,
                              hipStream_t stream) {
  const float* feats = (const float*)d_in[0];
  const float* trans = (const float*)d_in[1];
  const int*   tags  = (const int*)d_in[2];
  const int*   mask  = (const int*)d_in[3];
  float* out = (float*)d_out;
  (void)d_ws; (void)ws_size;

  crf_seg_kernel<<<NB, 512, 0, stream>>>(feats, trans, tags, mask, out);
}